// Round 2
// baseline (395.276 us; speedup 1.0000x reference)
//
#include <hip/hip_runtime.h>
#include <cstdint>
#include <cstddef>

// ExpertGather: Y[b,e,k,j] = sum_i X[b, ind[b,e,k], i] * W[e,i,j]
// B=4 T=4096 I=1024 E=16 K=512 J=1024
// fp16 MFMA grouped GEMM, m97-style async K-loop:
//   global_load_lds width=16 for A (gathered) and B, XOR-swizzled LDS chunks
//   (swizzle applied on the per-lane GLOBAL address; LDS fill is lane-ordered).

typedef float    floatx4 __attribute__((ext_vector_type(4)));
typedef _Float16 half8   __attribute__((ext_vector_type(8)));
typedef _Float16 half4v  __attribute__((ext_vector_type(4)));

constexpr int Bc = 4, Tc = 4096, Ic = 1024, Ec = 16, Kc = 512, Jc = 1024;
constexpr int BM = 128, BN = 128, BK = 64, NT = 256;

__device__ __forceinline__ void async16(const void* g, void* l) {
  __builtin_amdgcn_global_load_lds(
      (const __attribute__((address_space(1))) uint32_t*)g,
      (__attribute__((address_space(3))) uint32_t*)l, 16, 0, 0);
}

// ---------- pre-pass: X fp32 -> fp16 ----------
__global__ void cvt_x_kernel(const float* __restrict__ X, _Float16* __restrict__ Xh, int n4) {
  int i = blockIdx.x * blockDim.x + threadIdx.x;
  int stride = gridDim.x * blockDim.x;
  for (; i < n4; i += stride) {
    floatx4 v = ((const floatx4*)X)[i];
    half4v h;
    h.x = (_Float16)v.x; h.y = (_Float16)v.y; h.z = (_Float16)v.z; h.w = (_Float16)v.w;
    ((half4v*)Xh)[i] = h;
  }
}

// ---------- pre-pass: W [E][I][J] fp32 -> WT [E][J][I] fp16 ----------
__global__ void cvt_w_kernel(const float* __restrict__ W, _Float16* __restrict__ WT) {
  __shared__ float tile[64][65];
  int bid = blockIdx.x;
  int e  = bid >> 8;
  int i0 = ((bid >> 4) & 15) * 64;
  int j0 = (bid & 15) * 64;
  int tid = threadIdx.x;
  int r  = tid >> 4;
  int c4 = tid & 15;
  const float* src = W + ((size_t)e << 20) + (size_t)i0 * Jc + j0;
#pragma unroll
  for (int s = 0; s < 4; s++) {
    int rr = r + s * 16;
    floatx4 v = *(const floatx4*)(src + (size_t)rr * Jc + c4 * 4);
    tile[rr][c4 * 4 + 0] = v.x; tile[rr][c4 * 4 + 1] = v.y;
    tile[rr][c4 * 4 + 2] = v.z; tile[rr][c4 * 4 + 3] = v.w;
  }
  __syncthreads();
  int jj = tid >> 2;
  int ig = tid & 3;
  half8 hv0, hv1;
#pragma unroll
  for (int q = 0; q < 8; q++) hv0[q] = (_Float16)tile[ig * 16 + q][jj];
#pragma unroll
  for (int q = 0; q < 8; q++) hv1[q] = (_Float16)tile[ig * 16 + 8 + q][jj];
  _Float16* dst = WT + ((size_t)e << 20) + (size_t)(j0 + jj) * Ic + i0 + ig * 16;
  ((half8*)dst)[0] = hv0;
  ((half8*)dst)[1] = hv1;
}

// ---------- main grouped GEMM ----------
// LDS tiles: 128 rows x 64 halves (128 B/row), no padding (global_load_lds is
// lane-ordered). Data chunk c (8 halves) of row r stored at position c ^ (r&7):
// fragment ds_read_b128 then rotates across all 32 banks (2-way only = free).
// Fragment layouts (m89-verified): A/B: m(n)=lane&15, k=(lane>>4)*8+j.
// C/D: col=lane&15, row=(lane>>4)*4+reg.
__global__ __launch_bounds__(NT, 4) void gemm_kernel(
    const int* __restrict__ ind32,
    const _Float16* __restrict__ Xh, const _Float16* __restrict__ WT,
    float* __restrict__ Y) {
  __shared__ alignas(16) _Float16 As[BM * BK];  // 16 KB
  __shared__ alignas(16) _Float16 Bs[BN * BK];  // 16 KB
  __shared__ int rowid[BM];
  __shared__ int is64_s;

  const int tid = threadIdx.x;
  const int bid = blockIdx.x;
  const int tileid = bid & 31;          // 4 mt x 8 nt
  const int be = bid >> 5;              // 0..63
  const int mt = tileid >> 3;
  const int nt = tileid & 7;
  const int b = be >> 4, e = be & 15;
  const int k0 = mt * BM;
  const int j0 = nt * BN;

  // index dtype probe (int64 vs int32 storage)
  if (tid == 0) {
    int orv = 0;
    for (int q = 1; q < 256; q += 2) orv |= ind32[q];
    is64_s = (orv == 0) ? 1 : 0;
  }
  __syncthreads();
  if (tid < BM) {
    int idx = be * Kc + k0 + tid;
    rowid[tid] = is64_s ? ind32[2 * idx] : ind32[idx];
  }
  __syncthreads();

  const int lane = tid & 63;
  const int wave = tid >> 6;
  const int wm = (wave >> 1) * 64;
  const int wn = (wave & 1) * 64;
  const int quad = lane >> 4;
  const int tr = lane & 15;
  const int t7 = tr & 7;
  const int lr = lane >> 3;   // row within 8-row region
  const int cst = lane & 7;   // stored chunk position (lane-ordered)
  const int cdat = cst ^ lr;  // data chunk this lane fetches (XOR swizzle)

  // per-lane global base pointers for the 4 staging issues (reused all K-iters)
  const _Float16* aptr[4];
  const _Float16* bptr[4];
#pragma unroll
  for (int q = 0; q < 4; q++) {
    const int rowA = (wave * 4 + q) * 8 + lr;  // local tile row 0..127
    aptr[q] = Xh + ((size_t)b * Tc + rowid[rowA]) * Ic + cdat * 8;
    bptr[q] = WT + ((size_t)e * Jc + j0 + rowA) * Ic + cdat * 8;
  }

  floatx4 acc[4][4];
#pragma unroll
  for (int mi = 0; mi < 4; mi++)
#pragma unroll
    for (int ni = 0; ni < 4; ni++) acc[mi][ni] = {0.f, 0.f, 0.f, 0.f};

  for (int kk = 0; kk < Ic; kk += BK) {
#pragma unroll
    for (int q = 0; q < 4; q++)
      async16(aptr[q] + kk, &As[(wave * 4 + q) * 512]);
#pragma unroll
    for (int q = 0; q < 4; q++)
      async16(bptr[q] + kk, &Bs[(wave * 4 + q) * 512]);
    __syncthreads();  // compiler drains vmcnt before s_barrier

#pragma unroll
    for (int ks = 0; ks < 2; ks++) {
      const int cofs = ((ks * 4 + quad) ^ t7) * 8;  // swizzled chunk offset (halves)
      half8 af[4], bf[4];
#pragma unroll
      for (int mi = 0; mi < 4; mi++)
        af[mi] = *(const half8*)&As[(wm + mi * 16 + tr) * 64 + cofs];
#pragma unroll
      for (int ni = 0; ni < 4; ni++)
        bf[ni] = *(const half8*)&Bs[(wn + ni * 16 + tr) * 64 + cofs];
#pragma unroll
      for (int mi = 0; mi < 4; mi++)
#pragma unroll
        for (int ni = 0; ni < 4; ni++)
          acc[mi][ni] = __builtin_amdgcn_mfma_f32_16x16x32_f16(af[mi], bf[ni], acc[mi][ni], 0, 0, 0);
    }
    __syncthreads();
  }

  // epilogue: C/D col=lane&15, row=quad*4+reg
  float* Yb = Y + (size_t)be * Kc * Jc;
#pragma unroll
  for (int mi = 0; mi < 4; mi++) {
#pragma unroll
    for (int ni = 0; ni < 4; ni++) {
      const int col = j0 + wn + ni * 16 + tr;
#pragma unroll
      for (int r = 0; r < 4; r++) {
        const int row = k0 + wm + mi * 16 + quad * 4 + r;
        Yb[(size_t)row * Jc + col] = acc[mi][ni][r];
      }
    }
  }
}

extern "C" void kernel_launch(void* const* d_in, const int* in_sizes, int n_in,
                              void* d_out, int out_size, void* d_ws, size_t ws_size,
                              hipStream_t stream) {
  const float* X = (const float*)d_in[0];
  const int* ind = (const int*)d_in[1];
  const float* W = (const float*)d_in[2];
  float* Y = (float*)d_out;

  const size_t nx = (size_t)Bc * Tc * Ic;
  _Float16* Xh = (_Float16*)d_ws;
  _Float16* WT = Xh + nx;

  cvt_x_kernel<<<4096, NT, 0, stream>>>(X, Xh, (int)(nx / 4));
  cvt_w_kernel<<<Ec * 256, NT, 0, stream>>>(W, WT);
  const int gemm_grid = Bc * Ec * (Kc / BM) * (Jc / BN);  // 2048
  gemm_kernel<<<gemm_grid, NT, 0, stream>>>(ind, Xh, WT, Y);
}

// Round 3
// 325.290 us; speedup vs baseline: 1.2151x; 1.2151x over previous
//
#include <hip/hip_runtime.h>
#include <cstdint>
#include <cstddef>

// ExpertGather: Y[b,e,k,j] = sum_i X[b, ind[b,e,k], i] * W[e,i,j]
// B=4 T=4096 I=1024 E=16 K=512 J=1024
// fp16 MFMA grouped GEMM. Round 3: 256x256 tile (halves staging traffic),
// XCD-swizzled block mapping (B-tile L2 sharing), full-line LDS-staged epilogue
// (kills write amplification). global_load_lds(16B) + XOR chunk swizzle kept
// (round 2 verified: 0 bank conflicts).

typedef float    floatx4 __attribute__((ext_vector_type(4)));
typedef _Float16 half8   __attribute__((ext_vector_type(8)));

constexpr int Bc = 4, Tc = 4096, Ic = 1024, Ec = 16, Kc = 512, Jc = 1024;
constexpr int BM = 256, BN = 256, BK = 64, NT = 512;

__device__ __forceinline__ void async16(const void* g, void* l) {
  __builtin_amdgcn_global_load_lds(
      (const __attribute__((address_space(1))) uint32_t*)g,
      (__attribute__((address_space(3))) uint32_t*)l, 16, 0, 0);
}

// ---------- pre-pass: X fp32 -> fp16 (16B stores) ----------
__global__ void cvt_x_kernel(const float* __restrict__ X, _Float16* __restrict__ Xh, int n8) {
  int i = blockIdx.x * blockDim.x + threadIdx.x;
  int stride = gridDim.x * blockDim.x;
  for (; i < n8; i += stride) {
    floatx4 v0 = ((const floatx4*)X)[2 * i];
    floatx4 v1 = ((const floatx4*)X)[2 * i + 1];
    half8 h;
    h[0] = (_Float16)v0.x; h[1] = (_Float16)v0.y; h[2] = (_Float16)v0.z; h[3] = (_Float16)v0.w;
    h[4] = (_Float16)v1.x; h[5] = (_Float16)v1.y; h[6] = (_Float16)v1.z; h[7] = (_Float16)v1.w;
    ((half8*)Xh)[i] = h;
  }
}

// ---------- pre-pass: W [E][I][J] fp32 -> WT [E][J][I] fp16 ----------
__global__ void cvt_w_kernel(const float* __restrict__ W, _Float16* __restrict__ WT) {
  __shared__ float tile[64][65];
  int bid = blockIdx.x;
  int e  = bid >> 8;
  int i0 = ((bid >> 4) & 15) * 64;
  int j0 = (bid & 15) * 64;
  int tid = threadIdx.x;
  int r  = tid >> 4;
  int c4 = tid & 15;
  const float* src = W + ((size_t)e << 20) + (size_t)i0 * Jc + j0;
#pragma unroll
  for (int s = 0; s < 4; s++) {
    int rr = r + s * 16;
    floatx4 v = *(const floatx4*)(src + (size_t)rr * Jc + c4 * 4);
    tile[rr][c4 * 4 + 0] = v.x; tile[rr][c4 * 4 + 1] = v.y;
    tile[rr][c4 * 4 + 2] = v.z; tile[rr][c4 * 4 + 3] = v.w;
  }
  __syncthreads();
  int jj = tid >> 2;
  int ig = tid & 3;
  half8 hv0, hv1;
#pragma unroll
  for (int q = 0; q < 8; q++) hv0[q] = (_Float16)tile[ig * 16 + q][jj];
#pragma unroll
  for (int q = 0; q < 8; q++) hv1[q] = (_Float16)tile[ig * 16 + 8 + q][jj];
  _Float16* dst = WT + ((size_t)e << 20) + (size_t)(j0 + jj) * Ic + i0 + ig * 16;
  ((half8*)dst)[0] = hv0;
  ((half8*)dst)[1] = hv1;
}

// ---------- main grouped GEMM ----------
// Grid 512 = 8 chunks x 8 sharers x 8 XCD-slots. B-tile group g=(e,nt) has 8
// sharer blocks (b,mt) all at bid%8==g%8 -> same XCD -> B-tile L2-resident.
// LDS tile layout: row r, logical chunk c (8 halves) stored at chunk c^(r&7)
// (swizzle applied on the per-lane global address; lds fill is lane-ordered).
// MFMA layouts (m89-verified): A/B m(n)=lane&15, k=(lane>>4)*8+j;
// C/D col=lane&15, row=(lane>>4)*4+reg.
__global__ __launch_bounds__(NT, 2) void gemm_kernel(
    const int* __restrict__ ind32,
    const _Float16* __restrict__ Xh, const _Float16* __restrict__ WT,
    float* __restrict__ Y) {
  __shared__ alignas(16) unsigned char smem[(BM + BN) * BK * 2];  // 64 KB
  _Float16* As = (_Float16*)smem;                 // 256 rows x 64 halves
  _Float16* Bs = (_Float16*)(smem + BM * BK * 2); // 256 rows x 64 halves
  float* lbuf = (float*)smem;                     // epilogue reuse (32x257 fits)
  __shared__ int rowid[BM];
  __shared__ int is64_s;

  const int tid = threadIdx.x;
  const int bid = blockIdx.x;
  const int x = bid & 7, s = (bid >> 3) & 7, chunk = bid >> 6;
  const int g = chunk * 8 + x;       // 0..63 B-tile group
  const int e = g >> 2, nt = g & 3;  // expert, j-tile
  const int b = s >> 1, mt = s & 1;  // batch, k-tile
  const int be = b * Ec + e;
  const int k0 = mt * BM;
  const int j0 = nt * BN;

  // index dtype probe (int64 vs int32 storage)
  if (tid == 0) {
    int orv = 0;
    for (int q = 1; q < 256; q += 2) orv |= ind32[q];
    is64_s = (orv == 0) ? 1 : 0;
  }
  __syncthreads();
  if (tid < BM) {
    int idx = be * Kc + k0 + tid;
    rowid[tid] = is64_s ? ind32[2 * idx] : ind32[idx];
  }
  __syncthreads();

  const int lane = tid & 63;
  const int wave = tid >> 6;           // 0..7
  const int wmb = (wave >> 2) * 128;   // wave m base (2 rows of waves)
  const int wnb = (wave & 3) * 64;     // wave n base (4 cols of waves)
  const int quad = lane >> 4;
  const int tr = lane & 15;
  const int t7 = tr & 7;
  const int lr = lane >> 3;            // row within 8-row staging group
  const int cst = lane & 7;            // stored chunk position (lane-ordered)
  const int cdat = cst ^ lr;           // data chunk this lane fetches

  // per-lane global base pointers for staging (4 row-groups of 8 rows each)
  const _Float16* aptr[4];
  const _Float16* bptr[4];
#pragma unroll
  for (int q = 0; q < 4; q++) {
    const int rowA = (wave * 4 + q) * 8 + lr;  // 0..255
    aptr[q] = Xh + ((size_t)b * Tc + rowid[rowA]) * Ic + cdat * 8;
    bptr[q] = WT + ((size_t)e * Jc + j0 + rowA) * Ic + cdat * 8;
  }

  floatx4 acc[8][4];
#pragma unroll
  for (int mi = 0; mi < 8; mi++)
#pragma unroll
    for (int ni = 0; ni < 4; ni++) acc[mi][ni] = {0.f, 0.f, 0.f, 0.f};

  for (int kk = 0; kk < Ic; kk += BK) {
#pragma unroll
    for (int q = 0; q < 4; q++)
      async16(aptr[q] + kk, &As[(wave * 4 + q) * 512]);
#pragma unroll
    for (int q = 0; q < 4; q++)
      async16(bptr[q] + kk, &Bs[(wave * 4 + q) * 512]);
    __syncthreads();

#pragma unroll
    for (int ks = 0; ks < 2; ks++) {
      const int cofs = ((ks * 4 + quad) ^ t7) * 8;
      half8 bf[4];
#pragma unroll
      for (int ni = 0; ni < 4; ni++)
        bf[ni] = *(const half8*)&Bs[(wnb + ni * 16 + tr) * 64 + cofs];
#pragma unroll
      for (int mi = 0; mi < 8; mi++) {
        half8 af = *(const half8*)&As[(wmb + mi * 16 + tr) * 64 + cofs];
#pragma unroll
        for (int ni = 0; ni < 4; ni++)
          acc[mi][ni] = __builtin_amdgcn_mfma_f32_16x16x32_f16(af, bf[ni], acc[mi][ni], 0, 0, 0);
      }
    }
    __syncthreads();
  }

  // ---- epilogue: 8 passes of 32 rows x 256 cols through LDS, full-line stores
  constexpr int LST = 257;  // lbuf row stride (floats): pad breaks quad conflicts
  float* Yb = Y + (size_t)be * Kc * Jc;
#pragma unroll
  for (int pass = 0; pass < 8; pass++) {
    // rows [pass*32, pass*32+32) of the 256-row tile belong to waves with
    // wave>>2 == pass>>2, acc mi = (pass&3)*2 + {0,1}
    if ((wave >> 2) == (pass >> 2)) {
#pragma unroll
      for (int h = 0; h < 2; h++) {
        const int mi = (pass & 3) * 2 + h;
        const int rr = h * 16 + quad * 4;  // row within pass (+reg)
#pragma unroll
        for (int ni = 0; ni < 4; ni++) {
          const int col = wnb + ni * 16 + tr;
#pragma unroll
          for (int r = 0; r < 4; r++)
            lbuf[(rr + r) * LST + col] = acc[mi][ni][r];
        }
      }
    }
    __syncthreads();
    // cooperative store: 32 rows x 64 float4 = 2048 float4s / 512 threads
#pragma unroll
    for (int it = 0; it < 4; it++) {
      const int idx = tid + it * NT;
      const int rr = idx >> 6, c4 = idx & 63;
      floatx4 v = *(const floatx4*)&lbuf[rr * LST + c4 * 4];
      *(floatx4*)&Yb[(size_t)(k0 + pass * 32 + rr) * Jc + j0 + c4 * 4] = v;
    }
    __syncthreads();
  }
}

extern "C" void kernel_launch(void* const* d_in, const int* in_sizes, int n_in,
                              void* d_out, int out_size, void* d_ws, size_t ws_size,
                              hipStream_t stream) {
  const float* X = (const float*)d_in[0];
  const int* ind = (const int*)d_in[1];
  const float* W = (const float*)d_in[2];
  float* Y = (float*)d_out;

  const size_t nx = (size_t)Bc * Tc * Ic;
  _Float16* Xh = (_Float16*)d_ws;
  _Float16* WT = Xh + nx;

  cvt_x_kernel<<<2048, 256, 0, stream>>>(X, Xh, (int)(nx / 8));
  cvt_w_kernel<<<Ec * 256, 256, 0, stream>>>(W, WT);
  const int gemm_grid = (Bc * Ec) * (Kc / BM) * (Jc / BN) * 1;  // 64*2*4 = 512
  gemm_kernel<<<gemm_grid, NT, 0, stream>>>(ind, Xh, WT, Y);
}